// Round 9
// baseline (530.644 us; speedup 1.0000x reference)
//
#include <hip/hip_runtime.h>
#include <math.h>

#define HALF 64
#define LN_EPS 1e-5f

// gelu_tanh(x) = x * sigmoid(1.5957691*x + 0.0713549*x^3)
#define GC0 -2.3022082f
#define GC1 -0.1029438f

__device__ __forceinline__ float gelu_fast(float x) {
    const float x2 = x * x;
    const float z  = x * fmaf(GC1, x2, GC0);
    const float e  = __builtin_amdgcn_exp2f(z);
    const float sg = __builtin_amdgcn_rcpf(1.0f + e);
    return x * sg;
}

// ---------------------------------------------------------------------------
// init: zero cursor (grid-stride) + block0/wave0 computes analytic-LN consts.
// fp[0..13] = ux,uy,uz,c, Gxx,Gxy,Gxz,Gyy,Gyz,Gzz, px,py,pz,q
// ---------------------------------------------------------------------------
__global__ void __launch_bounds__(256) init_kernel(
    const float* __restrict__ W1, const float* __restrict__ b1,
    int* __restrict__ cursor, float* __restrict__ fp, int N)
{
    const int t = blockIdx.x * 256 + threadIdx.x;
    const int T = gridDim.x * 256;
    for (int i = t; i < N; i += T) cursor[i] = 0;
    if (blockIdx.x == 0 && threadIdx.x < 64) {
        const int k = threadIdx.x;
        const float w0 = W1[k], w1 = W1[HALF + k], w2 = W1[2 * HALF + k], bb = b1[k];
        float v[14] = { w0, w1, w2, bb,
                        w0 * w0, w0 * w1, w0 * w2, w1 * w1, w1 * w2, w2 * w2,
                        w0 * bb, w1 * bb, w2 * bb, bb * bb };
#pragma unroll
        for (int j = 0; j < 14; ++j) {
            float s = v[j];
#pragma unroll
            for (int off = 32; off; off >>= 1) s += __shfl_down(s, off, 64);
            if (k == 0) fp[j] = s * (1.0f / 64.0f);
        }
    }
}

// ---------------------------------------------------------------------------
// histogram of dst; atomic return value IS the edge's rank in its bucket —
// persist it so fill needs no atomics at all.
// ---------------------------------------------------------------------------
__global__ void __launch_bounds__(256) hist_kernel(
    const int* __restrict__ dst, int* __restrict__ cursor,
    int* __restrict__ rank, int E)
{
    const int e4 = (blockIdx.x * 256 + threadIdx.x) * 4;
    if (e4 + 3 < E) {
        const int4 d = *(const int4*)(dst + e4);
        int4 r;
        r.x = atomicAdd(&cursor[d.x], 1);
        r.y = atomicAdd(&cursor[d.y], 1);
        r.z = atomicAdd(&cursor[d.z], 1);
        r.w = atomicAdd(&cursor[d.w], 1);
        *(int4*)(rank + e4) = r;
    } else {
        for (int e = e4; e < E; ++e) rank[e] = atomicAdd(&cursor[dst[e]], 1);
    }
}

// ---------------------------------------------------------------------------
// single-block exclusive scan: cursor(counts) -> offsets[N+1].
// ---------------------------------------------------------------------------
__global__ void __launch_bounds__(1024) scan_kernel(
    const int* __restrict__ cursor, int* __restrict__ offsets, int N)
{
    __shared__ int wtot[16];
    __shared__ int wexc[16];
    __shared__ int stot;
    const int t = threadIdx.x;
    const int w = t >> 6, lane = t & 63;
    int carry = 0;
    for (int base = 0; base < N; base += 4096) {
        const int i0 = base + t * 4;
        int c[4];
        if (i0 + 3 < N) {
            *(int4*)c = *(const int4*)(cursor + i0);
        } else {
#pragma unroll
            for (int j = 0; j < 4; ++j) c[j] = (i0 + j < N) ? cursor[i0 + j] : 0;
        }
        const int s = c[0] + c[1] + c[2] + c[3];
        int incl = s;
#pragma unroll
        for (int off = 1; off < 64; off <<= 1) {
            const int v = __shfl_up(incl, off, 64);
            if (lane >= off) incl += v;
        }
        if (lane == 63) wtot[w] = incl;
        __syncthreads();
        if (t < 16) {
            const int v = wtot[t];
            int inc2 = v;
#pragma unroll
            for (int off = 1; off < 16; off <<= 1) {
                const int u = __shfl_up(inc2, off, 64);
                if (t >= off) inc2 += u;
            }
            wexc[t] = inc2 - v;
            if (t == 15) stot = inc2;
        }
        __syncthreads();
        int run = carry + wexc[w] + (incl - s);
#pragma unroll
        for (int j = 0; j < 4; ++j) {
            const int i = i0 + j;
            if (i < N) offsets[i] = run;
            run += c[j];
        }
        carry += stot;
        __syncthreads();
    }
    if (t == 0) offsets[N] = carry;
}

// ---------------------------------------------------------------------------
// fill (atomic-free): slot = offsets[dst] + rank[e]; geometry once per edge;
// scatter A[slot] grouped by dst.
// ---------------------------------------------------------------------------
__global__ void __launch_bounds__(256) fill_kernel(
    const int* __restrict__ ei, const int* __restrict__ rank,
    const float* __restrict__ pos, const float* __restrict__ fp,
    const int* __restrict__ offsets, float4* __restrict__ A, int E)
{
    const int e4 = (blockIdx.x * 256 + threadIdx.x) * 4;
    if (e4 >= E) return;

    int se[4], de[4], re[4];
    if (e4 + 3 < E) {
        *(int4*)se = *(const int4*)(ei + e4);
        *(int4*)de = *(const int4*)(ei + E + e4);
        *(int4*)re = *(const int4*)(rank + e4);
    } else {
        for (int j = 0; j < 4; ++j) {
            const int e = e4 + j;
            se[j] = (e < E) ? ei[e] : 0;
            de[j] = (e < E) ? ei[E + e] : 0;
            re[j] = (e < E) ? rank[e] : 0;
        }
    }
    const float ux = fp[0], uy = fp[1], uz = fp[2], cc = fp[3];
    const float Gxx = fp[4], Gxy = fp[5], Gxz = fp[6];
    const float Gyy = fp[7], Gyz = fp[8], Gzz = fp[9];
    const float px = fp[10], py = fp[11], pz = fp[12], qq = fp[13];

#pragma unroll
    for (int j = 0; j < 4; ++j) {
        const int e = e4 + j;
        if (e >= E) break;
        const int s = se[j], d = de[j];
        const float rx0 = pos[3 * d + 0] - pos[3 * s + 0];
        const float ry0 = pos[3 * d + 1] - pos[3 * s + 1];
        const float rz0 = pos[3 * d + 2] - pos[3 * s + 2];
        const float dist = sqrtf(rx0 * rx0 + ry0 * ry0 + rz0 * rz0);
        const float inv  = 1.0f / (dist + 1e-6f);
        const float rx = rx0 * inv, ry = ry0 * inv, rz = rz0 * inv;

        const float mu  = fmaf(ux, rx, fmaf(uy, ry, fmaf(uz, rz, cc)));
        const float ev2 = Gxx * rx * rx + Gyy * ry * ry + Gzz * rz * rz
                        + 2.0f * (Gxy * rx * ry + Gxz * rx * rz + Gyz * ry * rz
                                  + px * rx + py * ry + pz * rz) + qq;
        const float rstd = rsqrtf(ev2 - mu * mu + LN_EPS);

        const int slot = offsets[d] + re[j];
        A[slot] = make_float4(rx * rstd, ry * rstd, rz * rstd, rstd);
    }
}

// ---------------------------------------------------------------------------
// Node kernel: persistent grid-stride wave per node, lane = channel.
// __launch_bounds__(256, 8): force VGPR<=64 -> 8 blocks/CU -> grid 2048
// fully resident (R8 lesson: VGPR=84 capped at 4 blocks/CU, grid 1536 ran
// as 1.5 serialized rounds -> 28% occupancy). 4-deep load pipeline (fits
// the 64-VGPR budget); latency hidden by 8 waves/SIMD TLP.
// ---------------------------------------------------------------------------
__global__ void __launch_bounds__(256, 8) node_kernel(
    const float4* __restrict__ A,        // [E+8] CSR-ordered (padded)
    const int* __restrict__ offsets,     // [N+1]
    const float* __restrict__ W1, const float* __restrict__ b1,
    const float* __restrict__ ln_g, const float* __restrict__ ln_b,
    const float* __restrict__ W2, const float* __restrict__ b2,
    const float* __restrict__ fp,
    float* __restrict__ out, int N)
{
    __shared__ float sW2[HALF * HALF];
    __shared__ float sb2[HALF];
    const int tid = threadIdx.x;
    for (int i = tid; i < HALF * HALF; i += 256) sW2[i] = W2[i];
    if (tid < HALF) sb2[tid] = b2[tid];
    __syncthreads();

    const int lane = tid & 63;
    const float gl = ln_g[lane];
    const float C0 = gl * (W1[lane]            - fp[0]);
    const float C1 = gl * (W1[HALF + lane]     - fp[1]);
    const float C2 = gl * (W1[2 * HALF + lane] - fp[2]);
    const float C3 = gl * (b1[lane]            - fp[3]);
    const float Bl = ln_b[lane];
    const float b2l = sb2[lane];

    const int wv = blockIdx.x * 4 + (tid >> 6);
    const int nw = gridDim.x * 4;

    for (int n = wv; n < N; n += nw) {
        const int beg = offsets[n];
        const int cnt = offsets[n + 1] - beg;
        const float4* Ap = A + beg;

        float accA = 0.0f, accB = 0.0f;
        int i = 0;
        for (; i + 4 <= cnt; i += 4) {          // full chunks: no guards
            float4 aa[4];
#pragma unroll
            for (int j = 0; j < 4; ++j) aa[j] = Ap[i + j];
#pragma unroll
            for (int j = 0; j < 4; ++j) {
                const float x = fmaf(C0, aa[j].x, fmaf(C1, aa[j].y,
                                  fmaf(C2, aa[j].z, fmaf(C3, aa[j].w, Bl))));
                if (j & 1) accB += gelu_fast(x); else accA += gelu_fast(x);
            }
        }
        if (i < cnt) {                          // one guarded tail chunk (<4)
            const int rem = cnt - i;
            float4 aa[4];
#pragma unroll
            for (int j = 0; j < 4; ++j) aa[j] = Ap[i + j];   // pad-safe
#pragma unroll
            for (int j = 0; j < 4; ++j) {
                const float x = fmaf(C0, aa[j].x, fmaf(C1, aa[j].y,
                                  fmaf(C2, aa[j].z, fmaf(C3, aa[j].w, Bl))));
                const float g = gelu_fast(x);
                const float gm = (j < rem) ? g : 0.0f;
                if (j & 1) accB += gm; else accA += gm;
            }
        }
        const float acc = accA + accB;

        float o0 = 0.0f, o1 = 0.0f, o2 = 0.0f, o3 = 0.0f;
#pragma unroll
        for (int k = 0; k < HALF; k += 4) {     // 4 independent chains
            o0 = fmaf(__shfl(acc, k,     64), sW2[(k    ) * HALF + lane], o0);
            o1 = fmaf(__shfl(acc, k + 1, 64), sW2[(k + 1) * HALF + lane], o1);
            o2 = fmaf(__shfl(acc, k + 2, 64), sW2[(k + 2) * HALF + lane], o2);
            o3 = fmaf(__shfl(acc, k + 3, 64), sW2[(k + 3) * HALF + lane], o3);
        }
        const float o = (o0 + o1) + (o2 + o3);
        const float r = (cnt > 0) ? (o / (float)cnt + b2l) : 0.0f;
        float* orow = out + (size_t)n * (2 * HALF);
        orow[lane] = r;
        orow[HALF + lane] = 0.0f;
    }
}

// ---------------------------------------------------------------------------
extern "C" void kernel_launch(void* const* d_in, const int* in_sizes, int n_in,
                              void* d_out, int out_size, void* d_ws, size_t ws_size,
                              hipStream_t stream) {
    const float* pos = (const float*)d_in[0];
    const int*   ei  = (const int*)d_in[1];
    // d_in[2] = batch (unused)
    const float* W1  = (const float*)d_in[3];
    const float* b1  = (const float*)d_in[4];
    const float* g   = (const float*)d_in[5];
    const float* b   = (const float*)d_in[6];
    const float* W2  = (const float*)d_in[7];
    const float* b2  = (const float*)d_in[8];
    float* out = (float*)d_out;

    const int N = in_sizes[0] / 3;
    const int E = in_sizes[1] / 2;

    // workspace: A[E+8] float4 | cursor[N] | offsets[N+1] | rank[E] | fp[14]
    float4* A      = (float4*)d_ws;
    int* cursor    = (int*)(A + E + 8);
    int* offsets   = cursor + N;
    int* rank      = offsets + N + 1;
    float* fparams = (float*)(rank + E);

    init_kernel<<<128, 256, 0, stream>>>(W1, b1, cursor, fparams, N);
    hist_kernel<<<(E / 4 + 255) / 256, 256, 0, stream>>>(ei + E, cursor, rank, E);
    scan_kernel<<<1, 1024, 0, stream>>>(cursor, offsets, N);
    fill_kernel<<<(E / 4 + 255) / 256, 256, 0, stream>>>(ei, rank, pos, fparams,
                                                         offsets, A, E);
    // 2048 = 8 blocks/CU x 256 CUs — fully-resident persistent grid at <=64 VGPR
    node_kernel<<<2048, 256, 0, stream>>>(A, offsets, W1, b1, g, b, W2, b2,
                                          fparams, out, N);
}

// Round 10
// 426.827 us; speedup vs baseline: 1.2432x; 1.2432x over previous
//
#include <hip/hip_runtime.h>
#include <math.h>

#define HALF 64
#define LN_EPS 1e-5f

// gelu_tanh(x) = x * sigmoid(1.5957691*x + 0.0713549*x^3)
#define GC0 -2.3022082f
#define GC1 -0.1029438f

__device__ __forceinline__ float gelu_fast(float x) {
    const float x2 = x * x;
    const float z  = x * fmaf(GC1, x2, GC0);
    const float e  = __builtin_amdgcn_exp2f(z);
    const float sg = __builtin_amdgcn_rcpf(1.0f + e);
    return x * sg;
}

// ---------------------------------------------------------------------------
// histogram of dst; atomic return value IS the edge's rank in its bucket —
// persist it so fill needs no atomics at all.
// ---------------------------------------------------------------------------
__global__ void __launch_bounds__(256) hist_kernel(
    const int* __restrict__ dst, int* __restrict__ cursor,
    int* __restrict__ rank, int E)
{
    const int e4 = (blockIdx.x * 256 + threadIdx.x) * 4;
    if (e4 + 3 < E) {
        const int4 d = *(const int4*)(dst + e4);
        int4 r;
        r.x = atomicAdd(&cursor[d.x], 1);
        r.y = atomicAdd(&cursor[d.y], 1);
        r.z = atomicAdd(&cursor[d.z], 1);
        r.w = atomicAdd(&cursor[d.w], 1);
        *(int4*)(rank + e4) = r;
    } else {
        for (int e = e4; e < E; ++e) rank[e] = atomicAdd(&cursor[dst[e]], 1);
    }
}

// ---------------------------------------------------------------------------
// single-block exclusive scan: cursor(counts) -> offsets[N+1].
// Wave 0 first computes the analytic-LN constants (consumed by fill/node):
// fp[0..13] = ux,uy,uz,c, Gxx,Gxy,Gxz,Gyy,Gyz,Gzz, px,py,pz,q
// ---------------------------------------------------------------------------
__global__ void __launch_bounds__(1024) scan_kernel(
    const int* __restrict__ cursor, int* __restrict__ offsets,
    const float* __restrict__ W1, const float* __restrict__ b1,
    float* __restrict__ fp, int N)
{
    const int t = threadIdx.x;
    if (t < 64) {
        const float w0 = W1[t], w1 = W1[HALF + t], w2 = W1[2 * HALF + t], bb = b1[t];
        float v[14] = { w0, w1, w2, bb,
                        w0 * w0, w0 * w1, w0 * w2, w1 * w1, w1 * w2, w2 * w2,
                        w0 * bb, w1 * bb, w2 * bb, bb * bb };
#pragma unroll
        for (int j = 0; j < 14; ++j) {
            float s = v[j];
#pragma unroll
            for (int off = 32; off; off >>= 1) s += __shfl_down(s, off, 64);
            if (t == 0) fp[j] = s * (1.0f / 64.0f);
        }
    }

    __shared__ int wtot[16];
    __shared__ int wexc[16];
    __shared__ int stot;
    const int w = t >> 6, lane = t & 63;
    int carry = 0;
    for (int base = 0; base < N; base += 4096) {
        const int i0 = base + t * 4;
        int c[4];
        if (i0 + 3 < N) {
            *(int4*)c = *(const int4*)(cursor + i0);
        } else {
#pragma unroll
            for (int j = 0; j < 4; ++j) c[j] = (i0 + j < N) ? cursor[i0 + j] : 0;
        }
        const int s = c[0] + c[1] + c[2] + c[3];
        int incl = s;
#pragma unroll
        for (int off = 1; off < 64; off <<= 1) {
            const int v = __shfl_up(incl, off, 64);
            if (lane >= off) incl += v;
        }
        if (lane == 63) wtot[w] = incl;
        __syncthreads();
        if (t < 16) {
            const int v = wtot[t];
            int inc2 = v;
#pragma unroll
            for (int off = 1; off < 16; off <<= 1) {
                const int u = __shfl_up(inc2, off, 64);
                if (t >= off) inc2 += u;
            }
            wexc[t] = inc2 - v;
            if (t == 15) stot = inc2;
        }
        __syncthreads();
        int run = carry + wexc[w] + (incl - s);
#pragma unroll
        for (int j = 0; j < 4; ++j) {
            const int i = i0 + j;
            if (i < N) offsets[i] = run;
            run += c[j];
        }
        carry += stot;
        __syncthreads();
    }
    if (t == 0) offsets[N] = carry;
}

// ---------------------------------------------------------------------------
// fill (atomic-free): slot = offsets[dst] + rank[e]; geometry once per edge;
// scatter A[slot] grouped by dst.
// ---------------------------------------------------------------------------
__global__ void __launch_bounds__(256) fill_kernel(
    const int* __restrict__ ei, const int* __restrict__ rank,
    const float* __restrict__ pos, const float* __restrict__ fp,
    const int* __restrict__ offsets, float4* __restrict__ A, int E)
{
    const int e4 = (blockIdx.x * 256 + threadIdx.x) * 4;
    if (e4 >= E) return;

    int se[4], de[4], re[4];
    if (e4 + 3 < E) {
        *(int4*)se = *(const int4*)(ei + e4);
        *(int4*)de = *(const int4*)(ei + E + e4);
        *(int4*)re = *(const int4*)(rank + e4);
    } else {
        for (int j = 0; j < 4; ++j) {
            const int e = e4 + j;
            se[j] = (e < E) ? ei[e] : 0;
            de[j] = (e < E) ? ei[E + e] : 0;
            re[j] = (e < E) ? rank[e] : 0;
        }
    }
    const float ux = fp[0], uy = fp[1], uz = fp[2], cc = fp[3];
    const float Gxx = fp[4], Gxy = fp[5], Gxz = fp[6];
    const float Gyy = fp[7], Gyz = fp[8], Gzz = fp[9];
    const float px = fp[10], py = fp[11], pz = fp[12], qq = fp[13];

#pragma unroll
    for (int j = 0; j < 4; ++j) {
        const int e = e4 + j;
        if (e >= E) break;
        const int s = se[j], d = de[j];
        const float rx0 = pos[3 * d + 0] - pos[3 * s + 0];
        const float ry0 = pos[3 * d + 1] - pos[3 * s + 1];
        const float rz0 = pos[3 * d + 2] - pos[3 * s + 2];
        const float dist = sqrtf(rx0 * rx0 + ry0 * ry0 + rz0 * rz0);
        const float inv  = 1.0f / (dist + 1e-6f);
        const float rx = rx0 * inv, ry = ry0 * inv, rz = rz0 * inv;

        const float mu  = fmaf(ux, rx, fmaf(uy, ry, fmaf(uz, rz, cc)));
        const float ev2 = Gxx * rx * rx + Gyy * ry * ry + Gzz * rz * rz
                        + 2.0f * (Gxy * rx * ry + Gxz * rx * rz + Gyz * ry * rz
                                  + px * rx + py * ry + pz * rz) + qq;
        const float rstd = rsqrtf(ev2 - mu * mu + LN_EPS);

        const int slot = offsets[d] + re[j];
        A[slot] = make_float4(rx * rstd, ry * rstd, rz * rstd, rstd);
    }
}

// ---------------------------------------------------------------------------
// Node kernel: persistent grid-stride wave per node, lane = channel.
// __launch_bounds__(256, 6): VGPR cap ~85 — comfortably above the 4-deep
// pipeline's ~60 need (NO spill; R9 lesson: forcing cap 64 spilled 1.4 GB
// to scratch), and guarantees >=6 blocks/CU -> grid 1536 fully resident,
// balanced (R8 lesson: 1536 at 4 blocks/CU ran 1.5 serialized rounds).
// ---------------------------------------------------------------------------
__global__ void __launch_bounds__(256, 6) node_kernel(
    const float4* __restrict__ A,        // [E+8] CSR-ordered (padded)
    const int* __restrict__ offsets,     // [N+1]
    const float* __restrict__ W1, const float* __restrict__ b1,
    const float* __restrict__ ln_g, const float* __restrict__ ln_b,
    const float* __restrict__ W2, const float* __restrict__ b2,
    const float* __restrict__ fp,
    float* __restrict__ out, int N)
{
    __shared__ float sW2[HALF * HALF];
    __shared__ float sb2[HALF];
    const int tid = threadIdx.x;
    for (int i = tid; i < HALF * HALF; i += 256) sW2[i] = W2[i];
    if (tid < HALF) sb2[tid] = b2[tid];
    __syncthreads();

    const int lane = tid & 63;
    const float gl = ln_g[lane];
    const float C0 = gl * (W1[lane]            - fp[0]);
    const float C1 = gl * (W1[HALF + lane]     - fp[1]);
    const float C2 = gl * (W1[2 * HALF + lane] - fp[2]);
    const float C3 = gl * (b1[lane]            - fp[3]);
    const float Bl = ln_b[lane];
    const float b2l = sb2[lane];

    const int wv = blockIdx.x * 4 + (tid >> 6);
    const int nw = gridDim.x * 4;

    for (int n = wv; n < N; n += nw) {
        const int beg = offsets[n];
        const int cnt = offsets[n + 1] - beg;
        const float4* Ap = A + beg;

        float accA = 0.0f, accB = 0.0f;
        int i = 0;
        for (; i + 4 <= cnt; i += 4) {          // full chunks: no guards
            float4 aa[4];
#pragma unroll
            for (int j = 0; j < 4; ++j) aa[j] = Ap[i + j];
#pragma unroll
            for (int j = 0; j < 4; ++j) {
                const float x = fmaf(C0, aa[j].x, fmaf(C1, aa[j].y,
                                  fmaf(C2, aa[j].z, fmaf(C3, aa[j].w, Bl))));
                if (j & 1) accB += gelu_fast(x); else accA += gelu_fast(x);
            }
        }
        if (i < cnt) {                          // one guarded tail chunk (<4)
            const int rem = cnt - i;
            float4 aa[4];
#pragma unroll
            for (int j = 0; j < 4; ++j) aa[j] = Ap[i + j];   // pad-safe
#pragma unroll
            for (int j = 0; j < 4; ++j) {
                const float x = fmaf(C0, aa[j].x, fmaf(C1, aa[j].y,
                                  fmaf(C2, aa[j].z, fmaf(C3, aa[j].w, Bl))));
                const float g = gelu_fast(x);
                const float gm = (j < rem) ? g : 0.0f;
                if (j & 1) accB += gm; else accA += gm;
            }
        }
        const float acc = accA + accB;

        float o0 = 0.0f, o1 = 0.0f, o2 = 0.0f, o3 = 0.0f;
#pragma unroll
        for (int k = 0; k < HALF; k += 4) {     // 4 independent chains
            o0 = fmaf(__shfl(acc, k,     64), sW2[(k    ) * HALF + lane], o0);
            o1 = fmaf(__shfl(acc, k + 1, 64), sW2[(k + 1) * HALF + lane], o1);
            o2 = fmaf(__shfl(acc, k + 2, 64), sW2[(k + 2) * HALF + lane], o2);
            o3 = fmaf(__shfl(acc, k + 3, 64), sW2[(k + 3) * HALF + lane], o3);
        }
        const float o = (o0 + o1) + (o2 + o3);
        const float r = (cnt > 0) ? (o / (float)cnt + b2l) : 0.0f;
        float* orow = out + (size_t)n * (2 * HALF);
        orow[lane] = r;
        orow[HALF + lane] = 0.0f;
    }
}

// ---------------------------------------------------------------------------
extern "C" void kernel_launch(void* const* d_in, const int* in_sizes, int n_in,
                              void* d_out, int out_size, void* d_ws, size_t ws_size,
                              hipStream_t stream) {
    const float* pos = (const float*)d_in[0];
    const int*   ei  = (const int*)d_in[1];
    // d_in[2] = batch (unused)
    const float* W1  = (const float*)d_in[3];
    const float* b1  = (const float*)d_in[4];
    const float* g   = (const float*)d_in[5];
    const float* b   = (const float*)d_in[6];
    const float* W2  = (const float*)d_in[7];
    const float* b2  = (const float*)d_in[8];
    float* out = (float*)d_out;

    const int N = in_sizes[0] / 3;
    const int E = in_sizes[1] / 2;

    // workspace: A[E+8] float4 | cursor[N] | offsets[N+1] | rank[E] | fp[14]
    float4* A      = (float4*)d_ws;
    int* cursor    = (int*)(A + E + 8);
    int* offsets   = cursor + N;
    int* rank      = offsets + N + 1;
    float* fparams = (float*)(rank + E);

    hipMemsetAsync(cursor, 0, (size_t)N * sizeof(int), stream);
    hist_kernel<<<(E / 4 + 255) / 256, 256, 0, stream>>>(ei + E, cursor, rank, E);
    scan_kernel<<<1, 1024, 0, stream>>>(cursor, offsets, W1, b1, fparams, N);
    fill_kernel<<<(E / 4 + 255) / 256, 256, 0, stream>>>(ei, rank, pos, fparams,
                                                         offsets, A, E);
    // 1536 = 6 blocks/CU x 256 CUs — fully-resident, balanced persistent grid
    node_kernel<<<1536, 256, 0, stream>>>(A, offsets, W1, b1, g, b, W2, b2,
                                          fparams, out, N);
}

// Round 11
// 372.507 us; speedup vs baseline: 1.4245x; 1.1458x over previous
//
#include <hip/hip_runtime.h>
#include <math.h>

#define HALF 64
#define LN_EPS 1e-5f

// gelu_tanh(x) = x * sigmoid(1.5957691*x + 0.0713549*x^3)
#define GC0 -2.3022082f
#define GC1 -0.1029438f

__device__ __forceinline__ float gelu_fast(float x) {
    const float x2 = x * x;
    const float z  = x * fmaf(GC1, x2, GC0);
    const float e  = __builtin_amdgcn_exp2f(z);
    const float sg = __builtin_amdgcn_rcpf(1.0f + e);
    return x * sg;
}

// ---------------------------------------------------------------------------
// histogram of dst; atomic return value IS the edge's rank in its bucket —
// persist it so fill needs no atomics at all.
// ---------------------------------------------------------------------------
__global__ void __launch_bounds__(256) hist_kernel(
    const int* __restrict__ dst, int* __restrict__ cursor,
    int* __restrict__ rank, int E)
{
    const int e4 = (blockIdx.x * 256 + threadIdx.x) * 4;
    if (e4 + 3 < E) {
        const int4 d = *(const int4*)(dst + e4);
        int4 r;
        r.x = atomicAdd(&cursor[d.x], 1);
        r.y = atomicAdd(&cursor[d.y], 1);
        r.z = atomicAdd(&cursor[d.z], 1);
        r.w = atomicAdd(&cursor[d.w], 1);
        *(int4*)(rank + e4) = r;
    } else {
        for (int e = e4; e < E; ++e) rank[e] = atomicAdd(&cursor[dst[e]], 1);
    }
}

// ---------------------------------------------------------------------------
// single-block exclusive scan: cursor(counts) -> offsets[N+1].
// Wave 0 first computes the analytic-LN constants (consumed by fill/node):
// fp[0..13] = ux,uy,uz,c, Gxx,Gxy,Gxz,Gyy,Gyz,Gzz, px,py,pz,q
// ---------------------------------------------------------------------------
__global__ void __launch_bounds__(1024) scan_kernel(
    const int* __restrict__ cursor, int* __restrict__ offsets,
    const float* __restrict__ W1, const float* __restrict__ b1,
    float* __restrict__ fp, int N)
{
    const int t = threadIdx.x;
    if (t < 64) {
        const float w0 = W1[t], w1 = W1[HALF + t], w2 = W1[2 * HALF + t], bb = b1[t];
        float v[14] = { w0, w1, w2, bb,
                        w0 * w0, w0 * w1, w0 * w2, w1 * w1, w1 * w2, w2 * w2,
                        w0 * bb, w1 * bb, w2 * bb, bb * bb };
#pragma unroll
        for (int j = 0; j < 14; ++j) {
            float s = v[j];
#pragma unroll
            for (int off = 32; off; off >>= 1) s += __shfl_down(s, off, 64);
            if (t == 0) fp[j] = s * (1.0f / 64.0f);
        }
    }

    __shared__ int wtot[16];
    __shared__ int wexc[16];
    __shared__ int stot;
    const int w = t >> 6, lane = t & 63;
    int carry = 0;
    for (int base = 0; base < N; base += 4096) {
        const int i0 = base + t * 4;
        int c[4];
        if (i0 + 3 < N) {
            *(int4*)c = *(const int4*)(cursor + i0);
        } else {
#pragma unroll
            for (int j = 0; j < 4; ++j) c[j] = (i0 + j < N) ? cursor[i0 + j] : 0;
        }
        const int s = c[0] + c[1] + c[2] + c[3];
        int incl = s;
#pragma unroll
        for (int off = 1; off < 64; off <<= 1) {
            const int v = __shfl_up(incl, off, 64);
            if (lane >= off) incl += v;
        }
        if (lane == 63) wtot[w] = incl;
        __syncthreads();
        if (t < 16) {
            const int v = wtot[t];
            int inc2 = v;
#pragma unroll
            for (int off = 1; off < 16; off <<= 1) {
                const int u = __shfl_up(inc2, off, 64);
                if (t >= off) inc2 += u;
            }
            wexc[t] = inc2 - v;
            if (t == 15) stot = inc2;
        }
        __syncthreads();
        int run = carry + wexc[w] + (incl - s);
#pragma unroll
        for (int j = 0; j < 4; ++j) {
            const int i = i0 + j;
            if (i < N) offsets[i] = run;
            run += c[j];
        }
        carry += stot;
        __syncthreads();
    }
    if (t == 0) offsets[N] = carry;
}

// ---------------------------------------------------------------------------
// fill (atomic-free): slot = offsets[dst] + rank[e]; geometry once per edge;
// scatter A[slot] grouped by dst.
// ---------------------------------------------------------------------------
__global__ void __launch_bounds__(256) fill_kernel(
    const int* __restrict__ ei, const int* __restrict__ rank,
    const float* __restrict__ pos, const float* __restrict__ fp,
    const int* __restrict__ offsets, float4* __restrict__ A, int E)
{
    const int e4 = (blockIdx.x * 256 + threadIdx.x) * 4;
    if (e4 >= E) return;

    int se[4], de[4], re[4];
    if (e4 + 3 < E) {
        *(int4*)se = *(const int4*)(ei + e4);
        *(int4*)de = *(const int4*)(ei + E + e4);
        *(int4*)re = *(const int4*)(rank + e4);
    } else {
        for (int j = 0; j < 4; ++j) {
            const int e = e4 + j;
            se[j] = (e < E) ? ei[e] : 0;
            de[j] = (e < E) ? ei[E + e] : 0;
            re[j] = (e < E) ? rank[e] : 0;
        }
    }
    const float ux = fp[0], uy = fp[1], uz = fp[2], cc = fp[3];
    const float Gxx = fp[4], Gxy = fp[5], Gxz = fp[6];
    const float Gyy = fp[7], Gyz = fp[8], Gzz = fp[9];
    const float px = fp[10], py = fp[11], pz = fp[12], qq = fp[13];

#pragma unroll
    for (int j = 0; j < 4; ++j) {
        const int e = e4 + j;
        if (e >= E) break;
        const int s = se[j], d = de[j];
        const float rx0 = pos[3 * d + 0] - pos[3 * s + 0];
        const float ry0 = pos[3 * d + 1] - pos[3 * s + 1];
        const float rz0 = pos[3 * d + 2] - pos[3 * s + 2];
        const float dist = sqrtf(rx0 * rx0 + ry0 * ry0 + rz0 * rz0);
        const float inv  = 1.0f / (dist + 1e-6f);
        const float rx = rx0 * inv, ry = ry0 * inv, rz = rz0 * inv;

        const float mu  = fmaf(ux, rx, fmaf(uy, ry, fmaf(uz, rz, cc)));
        const float ev2 = Gxx * rx * rx + Gyy * ry * ry + Gzz * rz * rz
                        + 2.0f * (Gxy * rx * ry + Gxz * rx * rz + Gyz * ry * rz
                                  + px * rx + py * ry + pz * rz) + qq;
        const float rstd = rsqrtf(ev2 - mu * mu + LN_EPS);

        const int slot = offsets[d] + re[j];
        A[slot] = make_float4(rx * rstd, ry * rstd, rz * rstd, rstd);
    }
}

// ---------------------------------------------------------------------------
// Node kernel: persistent grid-stride wave per node, lane = channel.
// NO min-waves bound: the kernel wants ~84 VGPR (R9/R10 lesson: any forced
// cap under 64 spills ~0.5-1.4 GB to scratch). VGPR=84 -> 4 blocks/CU
// natural residency -> grid 1024 exactly resident and balanced (R8 lesson:
// grid 1536 at 4/CU ran as 1.5 serialized rounds).
// 8-deep load pipeline; epilogue = 4 independent shfl->fma chains.
// ---------------------------------------------------------------------------
__global__ void __launch_bounds__(256) node_kernel(
    const float4* __restrict__ A,        // [E+8] CSR-ordered (padded)
    const int* __restrict__ offsets,     // [N+1]
    const float* __restrict__ W1, const float* __restrict__ b1,
    const float* __restrict__ ln_g, const float* __restrict__ ln_b,
    const float* __restrict__ W2, const float* __restrict__ b2,
    const float* __restrict__ fp,
    float* __restrict__ out, int N)
{
    __shared__ float sW2[HALF * HALF];
    __shared__ float sb2[HALF];
    const int tid = threadIdx.x;
    for (int i = tid; i < HALF * HALF; i += 256) sW2[i] = W2[i];
    if (tid < HALF) sb2[tid] = b2[tid];
    __syncthreads();

    const int lane = tid & 63;
    const float gl = ln_g[lane];
    const float C0 = gl * (W1[lane]            - fp[0]);
    const float C1 = gl * (W1[HALF + lane]     - fp[1]);
    const float C2 = gl * (W1[2 * HALF + lane] - fp[2]);
    const float C3 = gl * (b1[lane]            - fp[3]);
    const float Bl = ln_b[lane];
    const float b2l = sb2[lane];

    const int wv = blockIdx.x * 4 + (tid >> 6);
    const int nw = gridDim.x * 4;

    for (int n = wv; n < N; n += nw) {
        const int beg = offsets[n];
        const int cnt = offsets[n + 1] - beg;
        const float4* Ap = A + beg;

        float accA = 0.0f, accB = 0.0f;
        int i = 0;
        for (; i + 8 <= cnt; i += 8) {          // full chunks: no guards
            float4 aa[8];
#pragma unroll
            for (int j = 0; j < 8; ++j) aa[j] = Ap[i + j];
#pragma unroll
            for (int j = 0; j < 8; ++j) {
                const float x = fmaf(C0, aa[j].x, fmaf(C1, aa[j].y,
                                  fmaf(C2, aa[j].z, fmaf(C3, aa[j].w, Bl))));
                if (j & 1) accB += gelu_fast(x); else accA += gelu_fast(x);
            }
        }
        if (i < cnt) {                          // one guarded tail chunk (<8)
            const int rem = cnt - i;
            float4 aa[8];
#pragma unroll
            for (int j = 0; j < 8; ++j) aa[j] = Ap[i + j];   // pad-safe
#pragma unroll
            for (int j = 0; j < 8; ++j) {
                const float x = fmaf(C0, aa[j].x, fmaf(C1, aa[j].y,
                                  fmaf(C2, aa[j].z, fmaf(C3, aa[j].w, Bl))));
                const float g = gelu_fast(x);
                const float gm = (j < rem) ? g : 0.0f;
                if (j & 1) accB += gm; else accA += gm;
            }
        }
        const float acc = accA + accB;

        float o0 = 0.0f, o1 = 0.0f, o2 = 0.0f, o3 = 0.0f;
#pragma unroll
        for (int k = 0; k < HALF; k += 4) {     // 4 independent chains
            o0 = fmaf(__shfl(acc, k,     64), sW2[(k    ) * HALF + lane], o0);
            o1 = fmaf(__shfl(acc, k + 1, 64), sW2[(k + 1) * HALF + lane], o1);
            o2 = fmaf(__shfl(acc, k + 2, 64), sW2[(k + 2) * HALF + lane], o2);
            o3 = fmaf(__shfl(acc, k + 3, 64), sW2[(k + 3) * HALF + lane], o3);
        }
        const float o = (o0 + o1) + (o2 + o3);
        const float r = (cnt > 0) ? (o / (float)cnt + b2l) : 0.0f;
        float* orow = out + (size_t)n * (2 * HALF);
        orow[lane] = r;
        orow[HALF + lane] = 0.0f;
    }
}

// ---------------------------------------------------------------------------
extern "C" void kernel_launch(void* const* d_in, const int* in_sizes, int n_in,
                              void* d_out, int out_size, void* d_ws, size_t ws_size,
                              hipStream_t stream) {
    const float* pos = (const float*)d_in[0];
    const int*   ei  = (const int*)d_in[1];
    // d_in[2] = batch (unused)
    const float* W1  = (const float*)d_in[3];
    const float* b1  = (const float*)d_in[4];
    const float* g   = (const float*)d_in[5];
    const float* b   = (const float*)d_in[6];
    const float* W2  = (const float*)d_in[7];
    const float* b2  = (const float*)d_in[8];
    float* out = (float*)d_out;

    const int N = in_sizes[0] / 3;
    const int E = in_sizes[1] / 2;

    // workspace: A[E+8] float4 | cursor[N] | offsets[N+1] | rank[E] | fp[14]
    float4* A      = (float4*)d_ws;
    int* cursor    = (int*)(A + E + 8);
    int* offsets   = cursor + N;
    int* rank      = offsets + N + 1;
    float* fparams = (float*)(rank + E);

    hipMemsetAsync(cursor, 0, (size_t)N * sizeof(int), stream);
    hist_kernel<<<(E / 4 + 255) / 256, 256, 0, stream>>>(ei + E, cursor, rank, E);
    scan_kernel<<<1, 1024, 0, stream>>>(cursor, offsets, W1, b1, fparams, N);
    fill_kernel<<<(E / 4 + 255) / 256, 256, 0, stream>>>(ei, rank, pos, fparams,
                                                         offsets, A, E);
    // 1024 = 4 blocks/CU x 256 CUs — natural residency at VGPR~84, balanced
    node_kernel<<<1024, 256, 0, stream>>>(A, offsets, W1, b1, g, b, W2, b2,
                                          fparams, out, N);
}

// Round 12
// 333.737 us; speedup vs baseline: 1.5900x; 1.1162x over previous
//
#include <hip/hip_runtime.h>
#include <math.h>

#define HALF 64
#define LN_EPS 1e-5f

// gelu_tanh(x) = x * sigmoid(1.5957691*x + 0.0713549*x^3)
#define GC0 -2.3022082f
#define GC1 -0.1029438f

__device__ __forceinline__ float gelu_fast(float x) {
    const float x2 = x * x;
    const float z  = x * fmaf(GC1, x2, GC0);
    const float e  = __builtin_amdgcn_exp2f(z);
    const float sg = __builtin_amdgcn_rcpf(1.0f + e);
    return x * sg;
}

// ---------------------------------------------------------------------------
// histogram of dst; atomic return value IS the edge's rank in its bucket
// ---------------------------------------------------------------------------
__global__ void __launch_bounds__(256) hist_kernel(
    const int* __restrict__ dst, int* __restrict__ cursor,
    int* __restrict__ rank, int E)
{
    const int e4 = (blockIdx.x * 256 + threadIdx.x) * 4;
    if (e4 + 3 < E) {
        const int4 d = *(const int4*)(dst + e4);
        int4 r;
        r.x = atomicAdd(&cursor[d.x], 1);
        r.y = atomicAdd(&cursor[d.y], 1);
        r.z = atomicAdd(&cursor[d.z], 1);
        r.w = atomicAdd(&cursor[d.w], 1);
        *(int4*)(rank + e4) = r;
    } else {
        for (int e = e4; e < E; ++e) rank[e] = atomicAdd(&cursor[dst[e]], 1);
    }
}

// ---------------------------------------------------------------------------
// single-block exclusive scan: cursor(counts) -> offsets[N+1].
// Wave 0 first computes the analytic-LN constants:
// fp[0..13] = ux,uy,uz,c, Gxx,Gxy,Gxz,Gyy,Gyz,Gzz, px,py,pz,q
// ---------------------------------------------------------------------------
__global__ void __launch_bounds__(1024) scan_kernel(
    const int* __restrict__ cursor, int* __restrict__ offsets,
    const float* __restrict__ W1, const float* __restrict__ b1,
    float* __restrict__ fp, int N)
{
    const int t = threadIdx.x;
    if (t < 64) {
        const float w0 = W1[t], w1 = W1[HALF + t], w2 = W1[2 * HALF + t], bb = b1[t];
        float v[14] = { w0, w1, w2, bb,
                        w0 * w0, w0 * w1, w0 * w2, w1 * w1, w1 * w2, w2 * w2,
                        w0 * bb, w1 * bb, w2 * bb, bb * bb };
#pragma unroll
        for (int j = 0; j < 14; ++j) {
            float s = v[j];
#pragma unroll
            for (int off = 32; off; off >>= 1) s += __shfl_down(s, off, 64);
            if (t == 0) fp[j] = s * (1.0f / 64.0f);
        }
    }

    __shared__ int wtot[16];
    __shared__ int wexc[16];
    __shared__ int stot;
    const int w = t >> 6, lane = t & 63;
    int carry = 0;
    for (int base = 0; base < N; base += 4096) {
        const int i0 = base + t * 4;
        int c[4];
        if (i0 + 3 < N) {
            *(int4*)c = *(const int4*)(cursor + i0);
        } else {
#pragma unroll
            for (int j = 0; j < 4; ++j) c[j] = (i0 + j < N) ? cursor[i0 + j] : 0;
        }
        const int s = c[0] + c[1] + c[2] + c[3];
        int incl = s;
#pragma unroll
        for (int off = 1; off < 64; off <<= 1) {
            const int v = __shfl_up(incl, off, 64);
            if (lane >= off) incl += v;
        }
        if (lane == 63) wtot[w] = incl;
        __syncthreads();
        if (t < 16) {
            const int v = wtot[t];
            int inc2 = v;
#pragma unroll
            for (int off = 1; off < 16; off <<= 1) {
                const int u = __shfl_up(inc2, off, 64);
                if (t >= off) inc2 += u;
            }
            wexc[t] = inc2 - v;
            if (t == 15) stot = inc2;
        }
        __syncthreads();
        int run = carry + wexc[w] + (incl - s);
#pragma unroll
        for (int j = 0; j < 4; ++j) {
            const int i = i0 + j;
            if (i < N) offsets[i] = run;
            run += c[j];
        }
        carry += stot;
        __syncthreads();
    }
    if (t == 0) offsets[N] = carry;
}

// ---------------------------------------------------------------------------
// fill (atomic-free): slot = offsets[dst] + rank[e]; geometry once per edge;
// scatter A[slot] grouped by dst.
// ---------------------------------------------------------------------------
__global__ void __launch_bounds__(256) fill_kernel(
    const int* __restrict__ ei, const int* __restrict__ rank,
    const float* __restrict__ pos, const float* __restrict__ fp,
    const int* __restrict__ offsets, float4* __restrict__ A, int E)
{
    const int e4 = (blockIdx.x * 256 + threadIdx.x) * 4;
    if (e4 >= E) return;

    int se[4], de[4], re[4];
    if (e4 + 3 < E) {
        *(int4*)se = *(const int4*)(ei + e4);
        *(int4*)de = *(const int4*)(ei + E + e4);
        *(int4*)re = *(const int4*)(rank + e4);
    } else {
        for (int j = 0; j < 4; ++j) {
            const int e = e4 + j;
            se[j] = (e < E) ? ei[e] : 0;
            de[j] = (e < E) ? ei[E + e] : 0;
            re[j] = (e < E) ? rank[e] : 0;
        }
    }
    const float ux = fp[0], uy = fp[1], uz = fp[2], cc = fp[3];
    const float Gxx = fp[4], Gxy = fp[5], Gxz = fp[6];
    const float Gyy = fp[7], Gyz = fp[8], Gzz = fp[9];
    const float px = fp[10], py = fp[11], pz = fp[12], qq = fp[13];

#pragma unroll
    for (int j = 0; j < 4; ++j) {
        const int e = e4 + j;
        if (e >= E) break;
        const int s = se[j], d = de[j];
        const float rx0 = pos[3 * d + 0] - pos[3 * s + 0];
        const float ry0 = pos[3 * d + 1] - pos[3 * s + 1];
        const float rz0 = pos[3 * d + 2] - pos[3 * s + 2];
        const float dist = sqrtf(rx0 * rx0 + ry0 * ry0 + rz0 * rz0);
        const float inv  = 1.0f / (dist + 1e-6f);
        const float rx = rx0 * inv, ry = ry0 * inv, rz = rz0 * inv;

        const float mu  = fmaf(ux, rx, fmaf(uy, ry, fmaf(uz, rz, cc)));
        const float ev2 = Gxx * rx * rx + Gyy * ry * ry + Gzz * rz * rz
                        + 2.0f * (Gxy * rx * ry + Gxz * rx * rz + Gyz * ry * rz
                                  + px * rx + py * ry + pz * rz) + qq;
        const float rstd = rsqrtf(ev2 - mu * mu + LN_EPS);

        const int slot = offsets[d] + re[j];
        A[slot] = make_float4(rx * rstd, ry * rstd, rz * rstd, rstd);
    }
}

// ---------------------------------------------------------------------------
// Node kernel (epilogue REMOVED): wave per node, lane = channel.
// x = C0*ax + C1*ay + C2*az + C3*aw + Bl; acc = sum gelu(x); writes
// hagg[n][lane] = acc/deg. No LDS, no shfl, no W2 -> low VGPR, plain
// one-wave-per-node launch (no persistence arithmetic).
// ---------------------------------------------------------------------------
__global__ void __launch_bounds__(256) node_kernel(
    const float4* __restrict__ A,        // [E+8] CSR-ordered (padded)
    const int* __restrict__ offsets,     // [N+1]
    const float* __restrict__ W1, const float* __restrict__ b1,
    const float* __restrict__ ln_g, const float* __restrict__ ln_b,
    const float* __restrict__ fp,
    float* __restrict__ hagg,            // [N,64] = (sum h)/deg
    int N)
{
    const int tid = threadIdx.x;
    const int lane = tid & 63;
    const int n = blockIdx.x * 4 + (tid >> 6);
    if (n >= N) return;

    const float gl = ln_g[lane];
    const float C0 = gl * (W1[lane]            - fp[0]);
    const float C1 = gl * (W1[HALF + lane]     - fp[1]);
    const float C2 = gl * (W1[2 * HALF + lane] - fp[2]);
    const float C3 = gl * (b1[lane]            - fp[3]);
    const float Bl = ln_b[lane];

    const int beg = offsets[n];
    const int cnt = offsets[n + 1] - beg;
    const float4* Ap = A + beg;

    float accA = 0.0f, accB = 0.0f;
    int i = 0;
    for (; i + 8 <= cnt; i += 8) {          // full chunks: no guards
        float4 aa[8];
#pragma unroll
        for (int j = 0; j < 8; ++j) aa[j] = Ap[i + j];
#pragma unroll
        for (int j = 0; j < 8; ++j) {
            const float x = fmaf(C0, aa[j].x, fmaf(C1, aa[j].y,
                              fmaf(C2, aa[j].z, fmaf(C3, aa[j].w, Bl))));
            if (j & 1) accB += gelu_fast(x); else accA += gelu_fast(x);
        }
    }
    if (i < cnt) {                          // one guarded tail chunk (<8)
        const int rem = cnt - i;
        float4 aa[8];
#pragma unroll
        for (int j = 0; j < 8; ++j) aa[j] = Ap[i + j];   // pad-safe
#pragma unroll
        for (int j = 0; j < 8; ++j) {
            const float x = fmaf(C0, aa[j].x, fmaf(C1, aa[j].y,
                              fmaf(C2, aa[j].z, fmaf(C3, aa[j].w, Bl))));
            const float g = gelu_fast(x);
            const float gm = (j < rem) ? g : 0.0f;
            if (j & 1) accB += gm; else accA += gm;
        }
    }
    const float acc = accA + accB;
    hagg[(size_t)n * HALF + lane] = (cnt > 0) ? acc / (float)cnt : 0.0f;
}

// ---------------------------------------------------------------------------
// out_kernel: dense [N,64] @ [64,64] + b2 -> out[N,0:64]; out[N,64:128]=0.
// 16 nodes per block; hagg tile in padded LDS (stride 65: conflict-free);
// W2 staged per block; each thread computes 4 output cols (float4 LDS reads).
// deg==0 rows forced to 0 (b2 must not leak in — reference semantics).
// ---------------------------------------------------------------------------
__global__ void __launch_bounds__(256) out_kernel(
    const float* __restrict__ hagg, const int* __restrict__ offsets,
    const float* __restrict__ W2, const float* __restrict__ b2,
    float* __restrict__ out, int N)
{
    __shared__ float sW2[HALF * HALF];     // 16 KB
    __shared__ float sb2[HALF];
    __shared__ float sh[16 * 65];          // padded: bank-conflict-free
    const int tid = threadIdx.x;
    for (int i = tid; i < HALF * HALF; i += 256) sW2[i] = W2[i];
    if (tid < HALF) sb2[tid] = b2[tid];

    const int n0 = blockIdx.x * 16;
    // stage hagg[n0:n0+16][0:64] -> sh (scalar coalesced, padded rows)
    for (int i = tid; i < 16 * HALF; i += 256) {
        const int row = i >> 6, col = i & 63;
        const int n = n0 + row;
        sh[row * 65 + col] = (n < N) ? hagg[(size_t)n * HALF + col] : 0.0f;
    }
    __syncthreads();

    const int nl = tid >> 4;               // 0..15 local node
    const int cg = (tid & 15) * 4;         // 4 output cols
    float o0 = 0.0f, o1 = 0.0f, o2 = 0.0f, o3 = 0.0f;
#pragma unroll
    for (int k = 0; k < HALF; ++k) {
        const float hk = sh[nl * 65 + k];
        const float4 wv = *(const float4*)(sW2 + k * HALF + cg);
        o0 = fmaf(hk, wv.x, o0);
        o1 = fmaf(hk, wv.y, o1);
        o2 = fmaf(hk, wv.z, o2);
        o3 = fmaf(hk, wv.w, o3);
    }
    const int n = n0 + nl;
    if (n < N) {
        const int deg = offsets[n + 1] - offsets[n];
        float4 res;
        if (deg > 0)
            res = make_float4(o0 + sb2[cg], o1 + sb2[cg + 1],
                              o2 + sb2[cg + 2], o3 + sb2[cg + 3]);
        else
            res = make_float4(0.0f, 0.0f, 0.0f, 0.0f);
        float* orow = out + (size_t)n * (2 * HALF);
        *(float4*)(orow + cg) = res;
        *(float4*)(orow + HALF + cg) = make_float4(0.0f, 0.0f, 0.0f, 0.0f);
    }
}

// ---------------------------------------------------------------------------
extern "C" void kernel_launch(void* const* d_in, const int* in_sizes, int n_in,
                              void* d_out, int out_size, void* d_ws, size_t ws_size,
                              hipStream_t stream) {
    const float* pos = (const float*)d_in[0];
    const int*   ei  = (const int*)d_in[1];
    // d_in[2] = batch (unused)
    const float* W1  = (const float*)d_in[3];
    const float* b1  = (const float*)d_in[4];
    const float* g   = (const float*)d_in[5];
    const float* b   = (const float*)d_in[6];
    const float* W2  = (const float*)d_in[7];
    const float* b2  = (const float*)d_in[8];
    float* out = (float*)d_out;

    const int N = in_sizes[0] / 3;
    const int E = in_sizes[1] / 2;

    // workspace: A[E+8] f4 | cursor[N] | offsets[N+1] | fp[16] | rank[E]...
    //            hagg[N*64] OVERLAYS rank (rank dead after fill) — ~52 MB
    float4* A      = (float4*)d_ws;
    int* cursor    = (int*)(A + E + 8);
    int* offsets   = cursor + N;
    float* fparams = (float*)(offsets + N + 1);
    int* rank      = (int*)(fparams + 16);
    float* hagg    = (float*)rank;       // overlay: rank dead after fill

    hipMemsetAsync(cursor, 0, (size_t)N * sizeof(int), stream);
    hist_kernel<<<(E / 4 + 255) / 256, 256, 0, stream>>>(ei + E, cursor, rank, E);
    scan_kernel<<<1, 1024, 0, stream>>>(cursor, offsets, W1, b1, fparams, N);
    fill_kernel<<<(E / 4 + 255) / 256, 256, 0, stream>>>(ei, rank, pos, fparams,
                                                         offsets, A, E);
    node_kernel<<<(N + 3) / 4, 256, 0, stream>>>(A, offsets, W1, b1, g, b,
                                                 fparams, hagg, N);
    out_kernel<<<(N + 15) / 16, 256, 0, stream>>>(hagg, offsets, W2, b2, out, N);
}

// Round 13
// 286.967 us; speedup vs baseline: 1.8491x; 1.1630x over previous
//
#include <hip/hip_runtime.h>
#include <math.h>

#define HALF 64
#define LN_EPS 1e-5f

// gelu_tanh(x) = x * sigmoid(1.5957691*x + 0.0713549*x^3)
#define GC0 -2.3022082f
#define GC1 -0.1029438f

__device__ __forceinline__ float gelu_fast(float x) {
    const float x2 = x * x;
    const float z  = x * fmaf(GC1, x2, GC0);
    const float e  = __builtin_amdgcn_exp2f(z);
    const float sg = __builtin_amdgcn_rcpf(1.0f + e);
    return x * sg;
}

// ---------------------------------------------------------------------------
// histogram of dst; atomic return value IS the edge's rank in its bucket
// ---------------------------------------------------------------------------
__global__ void __launch_bounds__(256) hist_kernel(
    const int* __restrict__ dst, int* __restrict__ cursor,
    int* __restrict__ rank, int E)
{
    const int e4 = (blockIdx.x * 256 + threadIdx.x) * 4;
    if (e4 + 3 < E) {
        const int4 d = *(const int4*)(dst + e4);
        int4 r;
        r.x = atomicAdd(&cursor[d.x], 1);
        r.y = atomicAdd(&cursor[d.y], 1);
        r.z = atomicAdd(&cursor[d.z], 1);
        r.w = atomicAdd(&cursor[d.w], 1);
        *(int4*)(rank + e4) = r;
    } else {
        for (int e = e4; e < E; ++e) rank[e] = atomicAdd(&cursor[dst[e]], 1);
    }
}

// ---------------------------------------------------------------------------
// PARALLEL exclusive scan (decoupled lookback): grid of blocks, each block
// scans a 4096-elem chunk; stat[b] = (sum<<2)|state, state 1=aggregate,
// 2=inclusive-prefix. 25 blocks all co-resident -> no deadlock. Block 0
// wave 0 also computes the analytic-LN constants:
// fp[0..13] = ux,uy,uz,c, Gxx,Gxy,Gxz,Gyy,Gyz,Gzz, px,py,pz,q
// ---------------------------------------------------------------------------
__global__ void __launch_bounds__(1024) scan_kernel(
    const int* __restrict__ cursor, int* __restrict__ offsets,
    int* __restrict__ stat,
    const float* __restrict__ W1, const float* __restrict__ b1,
    float* __restrict__ fp, int N)
{
    const int t = threadIdx.x;
    const int b = blockIdx.x;
    if (b == 0 && t < 64) {
        const float w0 = W1[t], w1 = W1[HALF + t], w2 = W1[2 * HALF + t], bb = b1[t];
        float v[14] = { w0, w1, w2, bb,
                        w0 * w0, w0 * w1, w0 * w2, w1 * w1, w1 * w2, w2 * w2,
                        w0 * bb, w1 * bb, w2 * bb, bb * bb };
#pragma unroll
        for (int j = 0; j < 14; ++j) {
            float s = v[j];
#pragma unroll
            for (int off = 32; off; off >>= 1) s += __shfl_down(s, off, 64);
            if (t == 0) fp[j] = s * (1.0f / 64.0f);
        }
    }

    __shared__ int wtot[16];
    __shared__ int wexc[16];
    __shared__ int stot;
    __shared__ int sPref;
    const int w = t >> 6, lane = t & 63;

    const int i0 = b * 4096 + t * 4;
    int c[4];
    if (i0 + 3 < N) {
        *(int4*)c = *(const int4*)(cursor + i0);
    } else {
#pragma unroll
        for (int j = 0; j < 4; ++j) c[j] = (i0 + j < N) ? cursor[i0 + j] : 0;
    }
    const int s = c[0] + c[1] + c[2] + c[3];
    int incl = s;
#pragma unroll
    for (int off = 1; off < 64; off <<= 1) {
        const int v = __shfl_up(incl, off, 64);
        if (lane >= off) incl += v;
    }
    if (lane == 63) wtot[w] = incl;
    __syncthreads();
    if (t < 16) {
        const int v = wtot[t];
        int inc2 = v;
#pragma unroll
        for (int off = 1; off < 16; off <<= 1) {
            const int u = __shfl_up(inc2, off, 64);
            if (t >= off) inc2 += u;
        }
        wexc[t] = inc2 - v;
        if (t == 15) stot = inc2;
    }
    __syncthreads();

    if (t == 0) {
        const int S = stot;
        if (b == 0) {
            sPref = 0;
            __hip_atomic_store(&stat[0], (S << 2) | 2, __ATOMIC_RELEASE,
                               __HIP_MEMORY_SCOPE_AGENT);
        } else {
            __hip_atomic_store(&stat[b], (S << 2) | 1, __ATOMIC_RELEASE,
                               __HIP_MEMORY_SCOPE_AGENT);
            int running = 0;
            int j = b - 1;
            while (true) {
                const int v = __hip_atomic_load(&stat[j], __ATOMIC_ACQUIRE,
                                                __HIP_MEMORY_SCOPE_AGENT);
                const int st = v & 3;
                if (st == 0) continue;          // predecessor not published yet
                running += v >> 2;
                if (st == 2) break;             // hit a full prefix
                --j;
            }
            sPref = running;
            __hip_atomic_store(&stat[b], ((running + S) << 2) | 2,
                               __ATOMIC_RELEASE, __HIP_MEMORY_SCOPE_AGENT);
        }
    }
    __syncthreads();

    int run = sPref + wexc[w] + (incl - s);
#pragma unroll
    for (int j = 0; j < 4; ++j) {
        const int i = i0 + j;
        if (i < N) offsets[i] = run;
        run += c[j];
    }
    if (t == 0 && b == (int)gridDim.x - 1) offsets[N] = sPref + stot;
}

// ---------------------------------------------------------------------------
// fill (atomic-free): slot = offsets[dst] + rank[e]; geometry once per edge;
// scatter A[slot] grouped by dst (scatter absorbed by L2/L3 — A is 25.6 MB).
// ---------------------------------------------------------------------------
__global__ void __launch_bounds__(256) fill_kernel(
    const int* __restrict__ ei, const int* __restrict__ rank,
    const float* __restrict__ pos, const float* __restrict__ fp,
    const int* __restrict__ offsets, float4* __restrict__ A, int E)
{
    const int e4 = (blockIdx.x * 256 + threadIdx.x) * 4;
    if (e4 >= E) return;

    int se[4], de[4], re[4];
    if (e4 + 3 < E) {
        *(int4*)se = *(const int4*)(ei + e4);
        *(int4*)de = *(const int4*)(ei + E + e4);
        *(int4*)re = *(const int4*)(rank + e4);
    } else {
        for (int j = 0; j < 4; ++j) {
            const int e = e4 + j;
            se[j] = (e < E) ? ei[e] : 0;
            de[j] = (e < E) ? ei[E + e] : 0;
            re[j] = (e < E) ? rank[e] : 0;
        }
    }
    const float ux = fp[0], uy = fp[1], uz = fp[2], cc = fp[3];
    const float Gxx = fp[4], Gxy = fp[5], Gxz = fp[6];
    const float Gyy = fp[7], Gyz = fp[8], Gzz = fp[9];
    const float px = fp[10], py = fp[11], pz = fp[12], qq = fp[13];

#pragma unroll
    for (int j = 0; j < 4; ++j) {
        const int e = e4 + j;
        if (e >= E) break;
        const int s = se[j], d = de[j];
        const float rx0 = pos[3 * d + 0] - pos[3 * s + 0];
        const float ry0 = pos[3 * d + 1] - pos[3 * s + 1];
        const float rz0 = pos[3 * d + 2] - pos[3 * s + 2];
        const float dist = sqrtf(rx0 * rx0 + ry0 * ry0 + rz0 * rz0);
        const float inv  = 1.0f / (dist + 1e-6f);
        const float rx = rx0 * inv, ry = ry0 * inv, rz = rz0 * inv;

        const float mu  = fmaf(ux, rx, fmaf(uy, ry, fmaf(uz, rz, cc)));
        const float ev2 = Gxx * rx * rx + Gyy * ry * ry + Gzz * rz * rz
                        + 2.0f * (Gxy * rx * ry + Gxz * rx * rz + Gyz * ry * rz
                                  + px * rx + py * ry + pz * rz) + qq;
        const float rstd = rsqrtf(ev2 - mu * mu + LN_EPS);

        const int slot = offsets[d] + re[j];
        A[slot] = make_float4(rx * rstd, ry * rstd, rz * rstd, rstd);
    }
}

// ---------------------------------------------------------------------------
// FUSED node+out kernel: 16 nodes/block (4 waves x 4 nodes each).
// Phase 1 (per wave, lane=channel): edge loop -> acc; sh[r][lane]=acc/deg.
// Phase 2 (after one barrier): dense 16x64 @ 64x64 GEMM vs LDS-staged W2
// (thread = (node, 4 cols), float4 LDS reads), write out + zero upper half.
// Removes the hagg global round-trip (51 MB) and one dispatch.
// ---------------------------------------------------------------------------
__global__ void __launch_bounds__(256) nodeout_kernel(
    const float4* __restrict__ A,        // [E+8] CSR-ordered (padded)
    const int* __restrict__ offsets,     // [N+1]
    const float* __restrict__ W1, const float* __restrict__ b1,
    const float* __restrict__ ln_g, const float* __restrict__ ln_b,
    const float* __restrict__ W2, const float* __restrict__ b2,
    const float* __restrict__ fp,
    float* __restrict__ out, int N)
{
    __shared__ float sW2[HALF * HALF];   // 16 KB
    __shared__ float sb2[HALF];
    __shared__ float sh[16 * 65];        // padded rows: conflict-free
    __shared__ int   sdeg[16];
    const int tid = threadIdx.x;
    for (int i = tid; i < HALF * HALF; i += 256) sW2[i] = W2[i];
    if (tid < HALF) sb2[tid] = b2[tid];

    const int lane = tid & 63, w = tid >> 6;
    const float gl = ln_g[lane];
    const float C0 = gl * (W1[lane]            - fp[0]);
    const float C1 = gl * (W1[HALF + lane]     - fp[1]);
    const float C2 = gl * (W1[2 * HALF + lane] - fp[2]);
    const float C3 = gl * (b1[lane]            - fp[3]);
    const float Bl = ln_b[lane];

    const int base = blockIdx.x * 16;

#pragma unroll
    for (int q = 0; q < 4; ++q) {
        const int r = w * 4 + q;
        const int n = base + r;
        float acc = 0.0f;
        int cnt = 0;
        if (n < N) {
            const int beg = offsets[n];
            cnt = offsets[n + 1] - beg;
            const float4* Ap = A + beg;
            float accA = 0.0f, accB = 0.0f;
            int i = 0;
            for (; i + 8 <= cnt; i += 8) {       // full chunks: no guards
                float4 aa[8];
#pragma unroll
                for (int j = 0; j < 8; ++j) aa[j] = Ap[i + j];
#pragma unroll
                for (int j = 0; j < 8; ++j) {
                    const float x = fmaf(C0, aa[j].x, fmaf(C1, aa[j].y,
                                      fmaf(C2, aa[j].z, fmaf(C3, aa[j].w, Bl))));
                    if (j & 1) accB += gelu_fast(x); else accA += gelu_fast(x);
                }
            }
            if (i < cnt) {                       // one guarded tail chunk (<8)
                const int rem = cnt - i;
                float4 aa[8];
#pragma unroll
                for (int j = 0; j < 8; ++j) aa[j] = Ap[i + j];   // pad-safe
#pragma unroll
                for (int j = 0; j < 8; ++j) {
                    const float x = fmaf(C0, aa[j].x, fmaf(C1, aa[j].y,
                                      fmaf(C2, aa[j].z, fmaf(C3, aa[j].w, Bl))));
                    const float g = gelu_fast(x);
                    const float gm = (j < rem) ? g : 0.0f;
                    if (j & 1) accB += gm; else accA += gm;
                }
            }
            acc = accA + accB;
        }
        sh[r * 65 + lane] = (cnt > 0) ? acc / (float)cnt : 0.0f;
        if (lane == 0) sdeg[r] = cnt;
    }
    __syncthreads();

    const int nl = tid >> 4;             // 0..15 local node
    const int cg = (tid & 15) * 4;       // 4 output cols
    float o0 = 0.0f, o1 = 0.0f, o2 = 0.0f, o3 = 0.0f;
#pragma unroll
    for (int k = 0; k < HALF; ++k) {
        const float hk = sh[nl * 65 + k];
        const float4 wv = *(const float4*)(sW2 + k * HALF + cg);
        o0 = fmaf(hk, wv.x, o0);
        o1 = fmaf(hk, wv.y, o1);
        o2 = fmaf(hk, wv.z, o2);
        o3 = fmaf(hk, wv.w, o3);
    }
    const int n = base + nl;
    if (n < N) {
        float4 res;
        if (sdeg[nl] > 0)
            res = make_float4(o0 + sb2[cg], o1 + sb2[cg + 1],
                              o2 + sb2[cg + 2], o3 + sb2[cg + 3]);
        else
            res = make_float4(0.0f, 0.0f, 0.0f, 0.0f);
        float* orow = out + (size_t)n * (2 * HALF);
        *(float4*)(orow + cg) = res;
        *(float4*)(orow + HALF + cg) = make_float4(0.0f, 0.0f, 0.0f, 0.0f);
    }
}

// ---------------------------------------------------------------------------
extern "C" void kernel_launch(void* const* d_in, const int* in_sizes, int n_in,
                              void* d_out, int out_size, void* d_ws, size_t ws_size,
                              hipStream_t stream) {
    const float* pos = (const float*)d_in[0];
    const int*   ei  = (const int*)d_in[1];
    // d_in[2] = batch (unused)
    const float* W1  = (const float*)d_in[3];
    const float* b1  = (const float*)d_in[4];
    const float* g   = (const float*)d_in[5];
    const float* b   = (const float*)d_in[6];
    const float* W2  = (const float*)d_in[7];
    const float* b2  = (const float*)d_in[8];
    float* out = (float*)d_out;

    const int N = in_sizes[0] / 3;
    const int E = in_sizes[1] / 2;

    // workspace: A[E+8] f4 | cursor[N] | stat[32] | offsets[N+1] | fp[16] | rank[E]
    float4* A      = (float4*)d_ws;
    int* cursor    = (int*)(A + E + 8);
    int* stat      = cursor + N;
    int* offsets   = stat + 32;
    float* fparams = (float*)(offsets + N + 1);
    int* rank      = (int*)(fparams + 16);

    const int nb = (N + 4095) / 4096;    // 25 for N=100k (all co-resident)

    hipMemsetAsync(cursor, 0, (size_t)(N + 32) * sizeof(int), stream);
    hist_kernel<<<(E / 4 + 255) / 256, 256, 0, stream>>>(ei + E, cursor, rank, E);
    scan_kernel<<<nb, 1024, 0, stream>>>(cursor, offsets, stat, W1, b1, fparams, N);
    fill_kernel<<<(E / 4 + 255) / 256, 256, 0, stream>>>(ei, rank, pos, fparams,
                                                         offsets, A, E);
    nodeout_kernel<<<(N + 15) / 16, 256, 0, stream>>>(A, offsets, W1, b1, g, b,
                                                      W2, b2, fparams, out, N);
}